// Round 1
// baseline (910.620 us; speedup 1.0000x reference)
//
#include <hip/hip_runtime.h>

// SingleAttention: B=16, S=2048, F=512, D_K=D_V=512, fp32 in/out.
// q = xq@Wq+bq; k = xk@Wk+bk; v = xv@Wv+bv; out = softmax(q k^T / sqrt(512)) v
//
// Pipeline:
//  1) wt_kernel:  WT_z[n][k] = (f16)W_z[k][n]   (B-operand wants [n][k] for contiguous k reads)
//  2) proj_kernel: f16 MFMA GEMM 128x128 tile, BK=32, fused fp32->f16 staging.
//       z=0: Q[s][d], z=1: K[s][d], z=2: Vt[b][d][s]  (A/B roles swapped so stores are row-major)
//  3) attn_kernel: flash attention, 8 waves x 16 Q rows, KVBLK=32,
//       K tile in LDS (XOR-swizzled), V frags direct from global Vt (L1/L2 served).

typedef _Float16 f16_t;
typedef _Float16 f16x8 __attribute__((ext_vector_type(8)));
typedef _Float16 f16x4 __attribute__((ext_vector_type(4)));
typedef float f32x4 __attribute__((ext_vector_type(4)));

#define MFMA16(a, b, c) __builtin_amdgcn_mfma_f32_16x16x32_f16((a), (b), (c), 0, 0, 0)

// ---------------- 1) weight transpose + f16 convert ----------------
__global__ __launch_bounds__(256) void wt_kernel(
    const float* __restrict__ Wq, const float* __restrict__ Wk, const float* __restrict__ Wv,
    f16_t* __restrict__ WTq, f16_t* __restrict__ WTk, f16_t* __restrict__ WTv)
{
    int idx = blockIdx.x * 256 + threadIdx.x;      // 3*512*512 threads total
    int z = idx >> 18;                             // 512*512 = 2^18
    int r = idx & ((1 << 18) - 1);
    int k = r >> 9;                                // 0..511
    int n = r & 511;                               // consecutive threads -> consecutive n (coalesced read)
    const float* W = (z == 0) ? Wq : (z == 1) ? Wk : Wv;
    f16_t* WT = (z == 0) ? WTq : (z == 1) ? WTk : WTv;
    WT[(long)n * 512 + k] = (f16_t)W[(long)k * 512 + n];
}

// ---------------- 2) projection GEMM ----------------
// C[m][n] = sum_k A[m][k] * BT[n][k] + bias
// z=0/1: A = x (f32, M=32768), BT = WT (f16, N=512), bias along n, out = Q/K [s][d] f16
// z=2:   A = WTv (f16, M=512), BT = xv (f32, N=32768), bias along m, out = Vt[b][d][s] f16
__global__ __launch_bounds__(256) void proj_kernel(
    const float* __restrict__ xq, const float* __restrict__ xk, const float* __restrict__ xv,
    const f16_t* __restrict__ WTq, const f16_t* __restrict__ WTk, const f16_t* __restrict__ WTv,
    const float* __restrict__ bq, const float* __restrict__ bk, const float* __restrict__ bv,
    f16_t* __restrict__ Qo, f16_t* __restrict__ Ko, f16_t* __restrict__ Vto)
{
    __shared__ f16_t As[128 * 32];
    __shared__ f16_t Bs[128 * 32];

    const int z = blockIdx.z;
    const int bx = blockIdx.x;
    const int tid = threadIdx.x;
    const int lane = tid & 63;
    const int w = tid >> 6;
    const int g = lane >> 4, cc = lane & 15;
    const int wr = w >> 1, wc = w & 1;

    const float* Af = nullptr; const f16_t* Ah = nullptr;
    const float* Bf = nullptr; const f16_t* Bh = nullptr;
    const float* bias;
    long m0, n0;
    if (z == 0)      { Af = xq;  Bh = WTq; bias = bq; m0 = (long)(bx >> 2) * 128; n0 = (long)(bx & 3) * 128; }
    else if (z == 1) { Af = xk;  Bh = WTk; bias = bk; m0 = (long)(bx >> 2) * 128; n0 = (long)(bx & 3) * 128; }
    else             { Ah = WTv; Bf = xv;  bias = bv; m0 = (long)(bx & 3) * 128; n0 = (long)(bx >> 2) * 128; }

    f32x4 acc[4][4];
    #pragma unroll
    for (int i = 0; i < 4; ++i)
        #pragma unroll
        for (int j = 0; j < 4; ++j) acc[i][j] = (f32x4){0.f, 0.f, 0.f, 0.f};

    for (int k0 = 0; k0 < 512; k0 += 32) {
        __syncthreads();
        if (Af) {
            // A: fp32 source, convert to f16 while staging. 128x32 floats = 1024 chunks of 4.
            #pragma unroll
            for (int it = 0; it < 4; ++it) {
                int ci = tid + it * 256;
                int row = ci >> 3, col = (ci & 7) << 2;
                f32x4 v = *(const f32x4*)(Af + (m0 + row) * 512 + k0 + col);
                f16x4 h; h[0] = (f16_t)v[0]; h[1] = (f16_t)v[1]; h[2] = (f16_t)v[2]; h[3] = (f16_t)v[3];
                *(f16x4*)&As[row * 32 + col] = h;
            }
            // B: f16 source. 128x32 halves = 512 chunks of 8.
            #pragma unroll
            for (int it = 0; it < 2; ++it) {
                int ci = tid + it * 256;
                int row = ci >> 2, col = (ci & 3) << 3;
                *(f16x8*)&Bs[row * 32 + col] = *(const f16x8*)(Bh + (n0 + row) * 512 + k0 + col);
            }
        } else {
            #pragma unroll
            for (int it = 0; it < 2; ++it) {
                int ci = tid + it * 256;
                int row = ci >> 2, col = (ci & 3) << 3;
                *(f16x8*)&As[row * 32 + col] = *(const f16x8*)(Ah + (m0 + row) * 512 + k0 + col);
            }
            #pragma unroll
            for (int it = 0; it < 4; ++it) {
                int ci = tid + it * 256;
                int row = ci >> 3, col = (ci & 7) << 2;
                f32x4 v = *(const f32x4*)(Bf + (n0 + row) * 512 + k0 + col);
                f16x4 h; h[0] = (f16_t)v[0]; h[1] = (f16_t)v[1]; h[2] = (f16_t)v[2]; h[3] = (f16_t)v[3];
                *(f16x4*)&Bs[row * 32 + col] = h;
            }
        }
        __syncthreads();

        f16x8 a[4], bb[4];
        #pragma unroll
        for (int mt = 0; mt < 4; ++mt) a[mt] = *(const f16x8*)&As[(wr * 64 + mt * 16 + cc) * 32 + g * 8];
        #pragma unroll
        for (int nt = 0; nt < 4; ++nt) bb[nt] = *(const f16x8*)&Bs[(wc * 64 + nt * 16 + cc) * 32 + g * 8];
        #pragma unroll
        for (int mt = 0; mt < 4; ++mt)
            #pragma unroll
            for (int nt = 0; nt < 4; ++nt)
                acc[mt][nt] = MFMA16(a[mt], bb[nt], acc[mt][nt]);
    }

    // C/D layout (16x16): col = lane&15, row = (lane>>4)*4 + i   [guide §3, m89-verified]
    if (z < 2) {
        f16_t* out = (z == 0) ? Qo : Ko;
        #pragma unroll
        for (int nt = 0; nt < 4; ++nt) {
            float bval = bias[n0 + wc * 64 + nt * 16 + cc];
            #pragma unroll
            for (int mt = 0; mt < 4; ++mt)
                #pragma unroll
                for (int i = 0; i < 4; ++i) {
                    long m = m0 + wr * 64 + mt * 16 + 4 * g + i;
                    long n = n0 + wc * 64 + nt * 16 + cc;
                    out[m * 512 + n] = (f16_t)(acc[mt][nt][i] + bval);
                }
        }
    } else {
        #pragma unroll
        for (int mt = 0; mt < 4; ++mt)
            #pragma unroll
            for (int i = 0; i < 4; ++i) {
                long m = m0 + wr * 64 + mt * 16 + 4 * g + i;   // d index
                float bval = bias[m];
                #pragma unroll
                for (int nt = 0; nt < 4; ++nt) {
                    long sg = n0 + wc * 64 + nt * 16 + cc;     // global s over all batches
                    long bidx = sg >> 11, sl = sg & 2047;
                    Vto[bidx * (512L * 2048) + m * 2048 + sl] = (f16_t)(acc[mt][nt][i] + bval);
                }
            }
    }
}

// ---------------- 3) flash attention ----------------
// 256 blocks = 16 batches x 16 q-tiles of 128 rows. 8 waves, each owns 16 Q rows.
// Per KV step (KVBLK=32): stage K tile -> LDS (swizzled), S = Q K^T (MFMA),
// online softmax (shfl-xor over 16-lane groups), P via per-wave LDS, O += P V (MFMA).
__global__ __launch_bounds__(512, 2) void attn_kernel(
    const f16_t* __restrict__ Q, const f16_t* __restrict__ K,
    const f16_t* __restrict__ Vt, float* __restrict__ out)
{
    __shared__ f16_t Ks[32 * 512];          // 32 KB, XOR-swizzled rows
    __shared__ f16_t Pl[8][16][40];         // per-wave P, rows padded to 40 (80 B, 16B-aligned)

    const int tid = threadIdx.x;
    const int w = tid >> 6, lane = tid & 63;
    const int g = lane >> 4, cc = lane & 15;
    const int bx = blockIdx.x;
    const int b = bx >> 4, qt = bx & 15;
    const long qrow = (long)b * 2048 + qt * 128 + w * 16;

    // Q fragments in registers: 16 rows x 512 -> 16 x f16x8 per lane (64 VGPR)
    f16x8 qf[16];
    {
        const f16_t* qp = Q + (qrow + cc) * 512;
        #pragma unroll
        for (int kc = 0; kc < 16; ++kc) qf[kc] = *(const f16x8*)(qp + kc * 32 + g * 8);
    }

    f32x4 O[32];
    #pragma unroll
    for (int t = 0; t < 32; ++t) O[t] = (f32x4){0.f, 0.f, 0.f, 0.f};
    float m_[4], l_[4];
    #pragma unroll
    for (int i = 0; i < 4; ++i) { m_[i] = -__builtin_inff(); l_[i] = 0.f; }

    const f16_t* Kb = K + (long)b * 2048 * 512;
    const f16_t* Vb = Vt + (long)b * 512 * 2048;
    char* KsB = (char*)Ks;
    const float scale = 0.044194173824159216f;   // 1/sqrt(512)
    const int sw0 = (cc & 7) << 4;

    for (int kv0 = 0; kv0 < 2048; kv0 += 32) {
        __syncthreads();   // previous iter's K reads complete before overwrite
        // stage K tile [32][512] f16 = 2048 x 16B chunks; swizzled dest (chunk ^= row&7)
        #pragma unroll
        for (int it = 0; it < 4; ++it) {
            int ci = tid + it * 512;
            int row = ci >> 6, cib = ci & 63;
            uint4 v = *(const uint4*)(Kb + (long)(kv0 + row) * 512 + (cib << 3));
            *(uint4*)(KsB + row * 1024 + ((cib ^ (row & 7)) << 4)) = v;
        }
        __syncthreads();

        // S[16 q][32 kv]: two 16x16 n-tiles (kv rows cc and 16+cc), K=512 over 16 chunks
        f32x4 s0 = (f32x4){0.f, 0.f, 0.f, 0.f}, s1 = (f32x4){0.f, 0.f, 0.f, 0.f};
        #pragma unroll
        for (int kc = 0; kc < 16; ++kc) {
            int colb = kc * 64 + g * 16;
            f16x8 k0f = *(const f16x8*)(KsB + cc * 1024        + (colb ^ sw0));
            f16x8 k1f = *(const f16x8*)(KsB + (16 + cc) * 1024 + (colb ^ sw0));
            s0 = MFMA16(qf[kc], k0f, s0);
            s1 = MFMA16(qf[kc], k1f, s1);
        }

        // online softmax; lane holds rows q=4g+i, col kv=cc (+16)
        float sv0[4], sv1[4], rmax[4];
        #pragma unroll
        for (int i = 0; i < 4; ++i) {
            sv0[i] = s0[i] * scale; sv1[i] = s1[i] * scale;
            rmax[i] = fmaxf(sv0[i], sv1[i]);
        }
        #pragma unroll
        for (int off = 1; off < 16; off <<= 1) {
            #pragma unroll
            for (int i = 0; i < 4; ++i)
                rmax[i] = fmaxf(rmax[i], __shfl_xor(rmax[i], off, 64));
        }
        float al[4]; bool chg = false;
        #pragma unroll
        for (int i = 0; i < 4; ++i) {
            float mn = fmaxf(m_[i], rmax[i]);
            chg = chg || (mn > m_[i]);
            al[i] = __expf(m_[i] - mn);
            m_[i] = mn;
        }
        float rs[4];
        #pragma unroll
        for (int i = 0; i < 4; ++i) {
            float e0 = __expf(sv0[i] - m_[i]);
            float e1 = __expf(sv1[i] - m_[i]);
            rs[i] = e0 + e1;
            Pl[w][4 * g + i][cc]      = (f16_t)e0;
            Pl[w][4 * g + i][16 + cc] = (f16_t)e1;
        }
        #pragma unroll
        for (int off = 1; off < 16; off <<= 1) {
            #pragma unroll
            for (int i = 0; i < 4; ++i)
                rs[i] += __shfl_xor(rs[i], off, 64);
        }
        if (__any(chg)) {       // wave-uniform; skip O-rescale when max unchanged
            #pragma unroll
            for (int i = 0; i < 4; ++i) l_[i] *= al[i];
            #pragma unroll
            for (int t = 0; t < 32; ++t) {
                #pragma unroll
                for (int i = 0; i < 4; ++i) O[t][i] *= al[i];
            }
        }
        #pragma unroll
        for (int i = 0; i < 4; ++i) l_[i] += rs[i];

        // PV: A = P (m=q=cc, k=kv=g*8+j), B = V (n=d=cc, k=kv) from Vt rows (contiguous kv)
        f16x8 pf = *(const f16x8*)&Pl[w][cc][g * 8];
        #pragma unroll
        for (int nt = 0; nt < 32; ++nt) {
            f16x8 vf = *(const f16x8*)(Vb + (long)(nt * 16 + cc) * 2048 + kv0 + g * 8);
            O[nt] = MFMA16(pf, vf, O[nt]);
        }
    }

    float* ob = out + (long)b * 2048 * 512 + (long)(qt * 128 + w * 16) * 512;
    #pragma unroll
    for (int nt = 0; nt < 32; ++nt) {
        #pragma unroll
        for (int i = 0; i < 4; ++i) {
            ob[(long)(4 * g + i) * 512 + nt * 16 + cc] = O[nt][i] * (1.0f / l_[i]);
        }
    }
}

// ---------------- launch ----------------
extern "C" void kernel_launch(void* const* d_in, const int* in_sizes, int n_in,
                              void* d_out, int out_size, void* d_ws, size_t ws_size,
                              hipStream_t stream)
{
    (void)in_sizes; (void)n_in; (void)out_size; (void)ws_size;
    const float* xq = (const float*)d_in[0];
    const float* xk = (const float*)d_in[1];
    const float* xv = (const float*)d_in[2];
    const float* Wq = (const float*)d_in[3];
    const float* bq = (const float*)d_in[4];
    const float* Wk = (const float*)d_in[5];
    const float* bk = (const float*)d_in[6];
    const float* Wv = (const float*)d_in[7];
    const float* bv = (const float*)d_in[8];
    float* out = (float*)d_out;

    // workspace layout (f16): 3x WT (512KB ea) + Q + K + Vt (32MB ea) ~= 98 MB
    f16_t* ws = (f16_t*)d_ws;
    f16_t* WTq = ws;
    f16_t* WTk = WTq + 512L * 512;
    f16_t* WTv = WTk + 512L * 512;
    f16_t* Qb  = WTv + 512L * 512;
    f16_t* Kb  = Qb + 32768L * 512;
    f16_t* Vtb = Kb + 32768L * 512;

    wt_kernel<<<3072, 256, 0, stream>>>(Wq, Wk, Wv, WTq, WTk, WTv);

    dim3 pgrid(1024, 1, 3);
    proj_kernel<<<pgrid, 256, 0, stream>>>(xq, xk, xv, WTq, WTk, WTv,
                                           bq, bk, bv, Qb, Kb, Vtb);

    attn_kernel<<<256, 512, 0, stream>>>(Qb, Kb, Vtb, out);
}

// Round 2
// 449.076 us; speedup vs baseline: 2.0278x; 2.0278x over previous
//
#include <hip/hip_runtime.h>

// SingleAttention: B=16, S=2048, F=512, D_K=D_V=512, fp32 in/out.
// q = xq@Wq+bq; k = xk@Wk+bk; v = xv@Wv+bv; out = softmax(q k^T / sqrt(512)) v
//
// Pipeline:
//  1) wt_kernel:  WT_z[n][k] = (f16)W_z[k][n]
//  2) proj_kernel: f16 MFMA GEMM 128x128 tile, BK=32, fused fp32->f16 staging.
//       z=0: Q[s][d], z=1: K[s][d], z=2: Vt[b][d][s]
//  3) attn_kernel v2: flash attention, 8 waves x 16 Q rows, KVBLK=32,
//       K AND V tiles double-buffered in LDS via global_load_lds (async),
//       chunk-permuted LDS layouts (conflict-free ds_read_b128),
//       2-phase schedule: issue next-tile loads before compute, one barrier/tile.

typedef _Float16 f16_t;
typedef _Float16 f16x8 __attribute__((ext_vector_type(8)));
typedef _Float16 f16x4 __attribute__((ext_vector_type(4)));
typedef float f32x4 __attribute__((ext_vector_type(4)));

#define MFMA16(a, b, c) __builtin_amdgcn_mfma_f32_16x16x32_f16((a), (b), (c), 0, 0, 0)

__device__ __forceinline__ void gload_lds16(const void* gsrc, void* ldst) {
    __builtin_amdgcn_global_load_lds(
        (const __attribute__((address_space(1))) unsigned int*)gsrc,
        (__attribute__((address_space(3))) unsigned int*)ldst,
        16, 0, 0);
}

// ---------------- 1) weight transpose + f16 convert ----------------
__global__ __launch_bounds__(256) void wt_kernel(
    const float* __restrict__ Wq, const float* __restrict__ Wk, const float* __restrict__ Wv,
    f16_t* __restrict__ WTq, f16_t* __restrict__ WTk, f16_t* __restrict__ WTv)
{
    int idx = blockIdx.x * 256 + threadIdx.x;
    int z = idx >> 18;
    int r = idx & ((1 << 18) - 1);
    int k = r >> 9;
    int n = r & 511;
    const float* W = (z == 0) ? Wq : (z == 1) ? Wk : Wv;
    f16_t* WT = (z == 0) ? WTq : (z == 1) ? WTk : WTv;
    WT[(long)n * 512 + k] = (f16_t)W[(long)k * 512 + n];
}

// ---------------- 2) projection GEMM ----------------
__global__ __launch_bounds__(256) void proj_kernel(
    const float* __restrict__ xq, const float* __restrict__ xk, const float* __restrict__ xv,
    const f16_t* __restrict__ WTq, const f16_t* __restrict__ WTk, const f16_t* __restrict__ WTv,
    const float* __restrict__ bq, const float* __restrict__ bk, const float* __restrict__ bv,
    f16_t* __restrict__ Qo, f16_t* __restrict__ Ko, f16_t* __restrict__ Vto)
{
    __shared__ f16_t As[128 * 32];
    __shared__ f16_t Bs[128 * 32];

    const int z = blockIdx.z;
    const int bx = blockIdx.x;
    const int tid = threadIdx.x;
    const int lane = tid & 63;
    const int w = tid >> 6;
    const int g = lane >> 4, cc = lane & 15;
    const int wr = w >> 1, wc = w & 1;

    const float* Af = nullptr; const f16_t* Ah = nullptr;
    const float* Bf = nullptr; const f16_t* Bh = nullptr;
    const float* bias;
    long m0, n0;
    if (z == 0)      { Af = xq;  Bh = WTq; bias = bq; m0 = (long)(bx >> 2) * 128; n0 = (long)(bx & 3) * 128; }
    else if (z == 1) { Af = xk;  Bh = WTk; bias = bk; m0 = (long)(bx >> 2) * 128; n0 = (long)(bx & 3) * 128; }
    else             { Ah = WTv; Bf = xv;  bias = bv; m0 = (long)(bx & 3) * 128; n0 = (long)(bx >> 2) * 128; }

    f32x4 acc[4][4];
    #pragma unroll
    for (int i = 0; i < 4; ++i)
        #pragma unroll
        for (int j = 0; j < 4; ++j) acc[i][j] = (f32x4){0.f, 0.f, 0.f, 0.f};

    for (int k0 = 0; k0 < 512; k0 += 32) {
        __syncthreads();
        if (Af) {
            #pragma unroll
            for (int it = 0; it < 4; ++it) {
                int ci = tid + it * 256;
                int row = ci >> 3, col = (ci & 7) << 2;
                f32x4 v = *(const f32x4*)(Af + (m0 + row) * 512 + k0 + col);
                f16x4 h; h[0] = (f16_t)v[0]; h[1] = (f16_t)v[1]; h[2] = (f16_t)v[2]; h[3] = (f16_t)v[3];
                *(f16x4*)&As[row * 32 + col] = h;
            }
            #pragma unroll
            for (int it = 0; it < 2; ++it) {
                int ci = tid + it * 256;
                int row = ci >> 2, col = (ci & 3) << 3;
                *(f16x8*)&Bs[row * 32 + col] = *(const f16x8*)(Bh + (n0 + row) * 512 + k0 + col);
            }
        } else {
            #pragma unroll
            for (int it = 0; it < 2; ++it) {
                int ci = tid + it * 256;
                int row = ci >> 2, col = (ci & 3) << 3;
                *(f16x8*)&As[row * 32 + col] = *(const f16x8*)(Ah + (m0 + row) * 512 + k0 + col);
            }
            #pragma unroll
            for (int it = 0; it < 4; ++it) {
                int ci = tid + it * 256;
                int row = ci >> 3, col = (ci & 7) << 2;
                f32x4 v = *(const f32x4*)(Bf + (n0 + row) * 512 + k0 + col);
                f16x4 h; h[0] = (f16_t)v[0]; h[1] = (f16_t)v[1]; h[2] = (f16_t)v[2]; h[3] = (f16_t)v[3];
                *(f16x4*)&Bs[row * 32 + col] = h;
            }
        }
        __syncthreads();

        f16x8 a[4], bb[4];
        #pragma unroll
        for (int mt = 0; mt < 4; ++mt) a[mt] = *(const f16x8*)&As[(wr * 64 + mt * 16 + cc) * 32 + g * 8];
        #pragma unroll
        for (int nt = 0; nt < 4; ++nt) bb[nt] = *(const f16x8*)&Bs[(wc * 64 + nt * 16 + cc) * 32 + g * 8];
        #pragma unroll
        for (int mt = 0; mt < 4; ++mt)
            #pragma unroll
            for (int nt = 0; nt < 4; ++nt)
                acc[mt][nt] = MFMA16(a[mt], bb[nt], acc[mt][nt]);
    }

    if (z < 2) {
        f16_t* out = (z == 0) ? Qo : Ko;
        #pragma unroll
        for (int nt = 0; nt < 4; ++nt) {
            float bval = bias[n0 + wc * 64 + nt * 16 + cc];
            #pragma unroll
            for (int mt = 0; mt < 4; ++mt)
                #pragma unroll
                for (int i = 0; i < 4; ++i) {
                    long m = m0 + wr * 64 + mt * 16 + 4 * g + i;
                    long n = n0 + wc * 64 + nt * 16 + cc;
                    out[m * 512 + n] = (f16_t)(acc[mt][nt][i] + bval);
                }
        }
    } else {
        #pragma unroll
        for (int mt = 0; mt < 4; ++mt)
            #pragma unroll
            for (int i = 0; i < 4; ++i) {
                long m = m0 + wr * 64 + mt * 16 + 4 * g + i;   // d index
                float bval = bias[m];
                #pragma unroll
                for (int nt = 0; nt < 4; ++nt) {
                    long sg = n0 + wc * 64 + nt * 16 + cc;
                    long bidx = sg >> 11, sl = sg & 2047;
                    Vto[bidx * (512L * 2048) + m * 2048 + sl] = (f16_t)(acc[mt][nt][i] + bval);
                }
            }
    }
}

// ---------------- 3) flash attention v2 ----------------
// 256 blocks (XCD-swizzled) = 16 batches x 16 q-tiles of 128 rows. 8 waves x 16 Q rows.
// KVBLK=32. Both K and V tiles double-buffered in LDS via global_load_lds.
// LDS layouts are chunk-permutations (16B granularity) chosen so every
// ds_read_b128 is 4 groups of 16 contiguous chunks -> conflict-free:
//   K: slot = c*32 + row   (c = 16B-chunk within row, 0..63; row = kv 0..31)
//   V: slot = g*512 + d    (g = kv-chunk 0..3; d = 0..511)
__global__ __launch_bounds__(512, 2) void attn_kernel(
    const f16_t* __restrict__ Q, const f16_t* __restrict__ K,
    const f16_t* __restrict__ Vt, float* __restrict__ out)
{
    extern __shared__ __align__(16) char smem[];
    char* KsB = smem;                          // [2][32768]
    char* VsB = smem + 65536;                  // [2][32768]
    f16_t* PlB = (f16_t*)(smem + 131072);      // [8][16][40] f16

    const int tid = threadIdx.x;
    const int w = tid >> 6, lane = tid & 63;
    const int g = lane >> 4, cc = lane & 15;
    // XCD-aware swizzle: nwg=256, 8 XCDs -> each XCD gets 2 full batches' tiles
    const int bx = (blockIdx.x & 7) * 32 + (blockIdx.x >> 3);
    const int b = bx >> 4, qt = bx & 15;
    const long qrow = (long)b * 2048 + qt * 128 + w * 16;

    // Q fragments in registers: 16 rows x 512 -> 16 x f16x8 per lane (64 VGPR)
    f16x8 qf[16];
    {
        const f16_t* qp = Q + (qrow + cc) * 512;
        #pragma unroll
        for (int kc = 0; kc < 16; ++kc) qf[kc] = *(const f16x8*)(qp + kc * 32 + g * 8);
    }

    f32x4 O[32];
    #pragma unroll
    for (int t = 0; t < 32; ++t) O[t] = (f32x4){0.f, 0.f, 0.f, 0.f};
    float m_[4], l_[4];
    #pragma unroll
    for (int i = 0; i < 4; ++i) { m_[i] = -__builtin_inff(); l_[i] = 0.f; }

    const f16_t* Kb = K + (long)b * 2048 * 512;
    const f16_t* Vb = Vt + (long)b * 512 * 2048;
    const float scale = 0.044194173824159216f;   // 1/sqrt(512)

    // Per-thread staging sources. 2048 chunks per tile, 8 waves, 4 instrs/thread.
    // slot = w*256 + it*64 + lane; advance by one tile per iteration.
    const f16_t* ksrc[4];
    const f16_t* vsrc[4];
    #pragma unroll
    for (int it = 0; it < 4; ++it) {
        int slot = w * 256 + it * 64 + lane;
        int c = slot >> 5, row = slot & 31;
        ksrc[it] = Kb + (long)row * 512 + c * 8;         // + kv0*512
        int gq = slot >> 9, d = slot & 511;
        vsrc[it] = Vb + (long)d * 2048 + gq * 8;         // + kv0
    }
    const int ldso = (w * 256) * 16;   // wave-uniform LDS dest base offset

    // prologue: stage tile 0 into buf 0
    #pragma unroll
    for (int it = 0; it < 4; ++it) {
        gload_lds16(ksrc[it], KsB + ldso + it * 1024);
        gload_lds16(vsrc[it], VsB + ldso + it * 1024);
        ksrc[it] += 32 * 512; vsrc[it] += 32;
    }
    asm volatile("s_waitcnt vmcnt(0)" ::: "memory");
    __syncthreads();

    int cur = 0;
    for (int t = 0; t < 64; ++t) {
        // issue next-tile loads (async into other buffer) BEFORE compute
        if (t < 63) {
            char* kd = KsB + (cur ^ 1) * 32768 + ldso;
            char* vd = VsB + (cur ^ 1) * 32768 + ldso;
            #pragma unroll
            for (int it = 0; it < 4; ++it) {
                gload_lds16(ksrc[it], kd + it * 1024);
                gload_lds16(vsrc[it], vd + it * 1024);
                ksrc[it] += 32 * 512; vsrc[it] += 32;
            }
        }

        const char* Kc = KsB + cur * 32768;
        const char* Vc = VsB + cur * 32768;

        // S[16 q][32 kv]: two 16x16 n-tiles, K=512 over 16 chunks
        f32x4 s0 = (f32x4){0.f, 0.f, 0.f, 0.f}, s1 = (f32x4){0.f, 0.f, 0.f, 0.f};
        __builtin_amdgcn_s_setprio(1);
        #pragma unroll
        for (int kc = 0; kc < 16; ++kc) {
            int c = kc * 4 + g;
            f16x8 k0f = *(const f16x8*)(Kc + (c * 32 + cc) * 16);
            f16x8 k1f = *(const f16x8*)(Kc + (c * 32 + 16 + cc) * 16);
            s0 = MFMA16(qf[kc], k0f, s0);
            s1 = MFMA16(qf[kc], k1f, s1);
        }
        __builtin_amdgcn_s_setprio(0);

        // online softmax; lane holds rows q=4g+i, col kv=cc (+16)
        float sv0[4], sv1[4], rmax[4];
        #pragma unroll
        for (int i = 0; i < 4; ++i) {
            sv0[i] = s0[i] * scale; sv1[i] = s1[i] * scale;
            rmax[i] = fmaxf(sv0[i], sv1[i]);
        }
        #pragma unroll
        for (int off = 1; off < 16; off <<= 1) {
            #pragma unroll
            for (int i = 0; i < 4; ++i)
                rmax[i] = fmaxf(rmax[i], __shfl_xor(rmax[i], off, 64));
        }
        float al[4]; bool chg = false;
        #pragma unroll
        for (int i = 0; i < 4; ++i) {
            float mn = fmaxf(m_[i], rmax[i]);
            chg = chg || (mn > m_[i]);
            al[i] = __expf(m_[i] - mn);
            m_[i] = mn;
        }
        float rs[4];
        #pragma unroll
        for (int i = 0; i < 4; ++i) {
            float e0 = __expf(sv0[i] - m_[i]);
            float e1 = __expf(sv1[i] - m_[i]);
            rs[i] = e0 + e1;
            PlB[(w * 16 + 4 * g + i) * 40 + cc]      = (f16_t)e0;
            PlB[(w * 16 + 4 * g + i) * 40 + 16 + cc] = (f16_t)e1;
        }
        #pragma unroll
        for (int off = 1; off < 16; off <<= 1) {
            #pragma unroll
            for (int i = 0; i < 4; ++i)
                rs[i] += __shfl_xor(rs[i], off, 64);
        }
        if (__any(chg)) {       // skip O-rescale when running max unchanged
            #pragma unroll
            for (int i = 0; i < 4; ++i) l_[i] *= al[i];
            #pragma unroll
            for (int t2 = 0; t2 < 32; ++t2) {
                #pragma unroll
                for (int i = 0; i < 4; ++i) O[t2][i] *= al[i];
            }
        }
        #pragma unroll
        for (int i = 0; i < 4; ++i) l_[i] += rs[i];

        // PV: A = P (m=q=cc, k=kv=g*8+j), B = V from LDS (n=d, k=kv)
        f16x8 pf = *(const f16x8*)&PlB[(w * 16 + cc) * 40 + g * 8];
        __builtin_amdgcn_s_setprio(1);
        #pragma unroll
        for (int nt = 0; nt < 32; ++nt) {
            f16x8 vf = *(const f16x8*)(Vc + (g * 512 + nt * 16 + cc) * 16);
            O[nt] = MFMA16(pf, vf, O[nt]);
        }
        __builtin_amdgcn_s_setprio(0);

        asm volatile("s_waitcnt vmcnt(0)" ::: "memory");
        __syncthreads();
        cur ^= 1;
    }

    float* ob = out + (long)b * 2048 * 512 + (long)(qt * 128 + w * 16) * 512;
    #pragma unroll
    for (int nt = 0; nt < 32; ++nt) {
        #pragma unroll
        for (int i = 0; i < 4; ++i) {
            ob[(long)(4 * g + i) * 512 + nt * 16 + cc] = O[nt][i] * (1.0f / l_[i]);
        }
    }
}

// ---------------- launch ----------------
extern "C" void kernel_launch(void* const* d_in, const int* in_sizes, int n_in,
                              void* d_out, int out_size, void* d_ws, size_t ws_size,
                              hipStream_t stream)
{
    (void)in_sizes; (void)n_in; (void)out_size; (void)ws_size;
    const float* xq = (const float*)d_in[0];
    const float* xk = (const float*)d_in[1];
    const float* xv = (const float*)d_in[2];
    const float* Wq = (const float*)d_in[3];
    const float* bq = (const float*)d_in[4];
    const float* Wk = (const float*)d_in[5];
    const float* bk = (const float*)d_in[6];
    const float* Wv = (const float*)d_in[7];
    const float* bv = (const float*)d_in[8];
    float* out = (float*)d_out;

    f16_t* ws = (f16_t*)d_ws;
    f16_t* WTq = ws;
    f16_t* WTk = WTq + 512L * 512;
    f16_t* WTv = WTk + 512L * 512;
    f16_t* Qb  = WTv + 512L * 512;
    f16_t* Kb  = Qb + 32768L * 512;
    f16_t* Vtb = Kb + 32768L * 512;

    wt_kernel<<<3072, 256, 0, stream>>>(Wq, Wk, Wv, WTq, WTk, WTv);

    dim3 pgrid(1024, 1, 3);
    proj_kernel<<<pgrid, 256, 0, stream>>>(xq, xk, xv, WTq, WTk, WTv,
                                           bq, bk, bv, Qb, Kb, Vtb);

    // dynamic LDS: 2x32KB K + 2x32KB V + 10.25KB P = 141312 B
    attn_kernel<<<256, 512, 141312, stream>>>(Qb, Kb, Vtb, out);
}

// Round 4
// 412.470 us; speedup vs baseline: 2.2077x; 1.0887x over previous
//
#include <hip/hip_runtime.h>

// SingleAttention: B=16, S=2048, F=512, D_K=D_V=512, fp32 in/out.
// q = xq@Wq+bq; k = xk@Wk+bk; v = xv@Wv+bv; out = softmax(q k^T / sqrt(512)) v
//
// Pipeline:
//  1) wt_kernel:  WT_z[n][k] = (f16)W_z[k][n]
//  2) proj_kernel: f16 MFMA GEMM 128x128 tile, BK=32, fused fp32->f16 staging.
//       z=0: Q[s][d] (pre-scaled by 1/sqrt(512)), z=1: K[s][d], z=2: Vt[b][d][s]
//  3) attn_kernel v4: flash attention, 8 waves x 16 Q rows, KVBLK=32.
//       K/V double-buffered via global_load_lds with COALESCED sources.
//       K: linear row-major LDS rows; source chunks XOR-swizzled within each
//          1KB row; read side applies the XOR IN THE PER-LANE ADDRESS via two
//          precomputed bases (even/odd u) -> wave-consistent MFMA operands.
//          (v3 bug: folding the XOR into the qf[] index was per-lane -> lanes
//           disagreed on the d-window inside one MFMA. Fixed here.)
//       V: slot = 5*d + c (stride-5 odd => d-column reads spread bank quads).

typedef _Float16 f16_t;
typedef _Float16 f16x8 __attribute__((ext_vector_type(8)));
typedef _Float16 f16x4 __attribute__((ext_vector_type(4)));
typedef float f32x4 __attribute__((ext_vector_type(4)));

#define MFMA16(a, b, c) __builtin_amdgcn_mfma_f32_16x16x32_f16((a), (b), (c), 0, 0, 0)

__device__ __forceinline__ void gload_lds16(const void* gsrc, void* ldst) {
    __builtin_amdgcn_global_load_lds(
        (const __attribute__((address_space(1))) unsigned int*)gsrc,
        (__attribute__((address_space(3))) unsigned int*)ldst,
        16, 0, 0);
}

// ---------------- 1) weight transpose + f16 convert ----------------
__global__ __launch_bounds__(256) void wt_kernel(
    const float* __restrict__ Wq, const float* __restrict__ Wk, const float* __restrict__ Wv,
    f16_t* __restrict__ WTq, f16_t* __restrict__ WTk, f16_t* __restrict__ WTv)
{
    int idx = blockIdx.x * 256 + threadIdx.x;
    int z = idx >> 18;
    int r = idx & ((1 << 18) - 1);
    int k = r >> 9;
    int n = r & 511;
    const float* W = (z == 0) ? Wq : (z == 1) ? Wk : Wv;
    f16_t* WT = (z == 0) ? WTq : (z == 1) ? WTk : WTv;
    WT[(long)n * 512 + k] = (f16_t)W[(long)k * 512 + n];
}

// ---------------- 2) projection GEMM ----------------
__global__ __launch_bounds__(256) void proj_kernel(
    const float* __restrict__ xq, const float* __restrict__ xk, const float* __restrict__ xv,
    const f16_t* __restrict__ WTq, const f16_t* __restrict__ WTk, const f16_t* __restrict__ WTv,
    const float* __restrict__ bq, const float* __restrict__ bk, const float* __restrict__ bv,
    f16_t* __restrict__ Qo, f16_t* __restrict__ Ko, f16_t* __restrict__ Vto)
{
    __shared__ f16_t As[128 * 32];
    __shared__ f16_t Bs[128 * 32];

    const int z = blockIdx.z;
    const int bx = blockIdx.x;
    const int tid = threadIdx.x;
    const int lane = tid & 63;
    const int w = tid >> 6;
    const int g = lane >> 4, cc = lane & 15;
    const int wr = w >> 1, wc = w & 1;

    const float* Af = nullptr; const f16_t* Ah = nullptr;
    const float* Bf = nullptr; const f16_t* Bh = nullptr;
    const float* bias;
    long m0, n0;
    if (z == 0)      { Af = xq;  Bh = WTq; bias = bq; m0 = (long)(bx >> 2) * 128; n0 = (long)(bx & 3) * 128; }
    else if (z == 1) { Af = xk;  Bh = WTk; bias = bk; m0 = (long)(bx >> 2) * 128; n0 = (long)(bx & 3) * 128; }
    else             { Ah = WTv; Bf = xv;  bias = bv; m0 = (long)(bx & 3) * 128; n0 = (long)(bx >> 2) * 128; }

    f32x4 acc[4][4];
    #pragma unroll
    for (int i = 0; i < 4; ++i)
        #pragma unroll
        for (int j = 0; j < 4; ++j) acc[i][j] = (f32x4){0.f, 0.f, 0.f, 0.f};

    for (int k0 = 0; k0 < 512; k0 += 32) {
        __syncthreads();
        if (Af) {
            #pragma unroll
            for (int it = 0; it < 4; ++it) {
                int ci = tid + it * 256;
                int row = ci >> 3, col = (ci & 7) << 2;
                f32x4 v = *(const f32x4*)(Af + (m0 + row) * 512 + k0 + col);
                f16x4 h; h[0] = (f16_t)v[0]; h[1] = (f16_t)v[1]; h[2] = (f16_t)v[2]; h[3] = (f16_t)v[3];
                *(f16x4*)&As[row * 32 + col] = h;
            }
            #pragma unroll
            for (int it = 0; it < 2; ++it) {
                int ci = tid + it * 256;
                int row = ci >> 2, col = (ci & 3) << 3;
                *(f16x8*)&Bs[row * 32 + col] = *(const f16x8*)(Bh + (n0 + row) * 512 + k0 + col);
            }
        } else {
            #pragma unroll
            for (int it = 0; it < 2; ++it) {
                int ci = tid + it * 256;
                int row = ci >> 2, col = (ci & 3) << 3;
                *(f16x8*)&As[row * 32 + col] = *(const f16x8*)(Ah + (m0 + row) * 512 + k0 + col);
            }
            #pragma unroll
            for (int it = 0; it < 4; ++it) {
                int ci = tid + it * 256;
                int row = ci >> 3, col = (ci & 7) << 2;
                f32x4 v = *(const f32x4*)(Bf + (n0 + row) * 512 + k0 + col);
                f16x4 h; h[0] = (f16_t)v[0]; h[1] = (f16_t)v[1]; h[2] = (f16_t)v[2]; h[3] = (f16_t)v[3];
                *(f16x4*)&Bs[row * 32 + col] = h;
            }
        }
        __syncthreads();

        f16x8 a[4], bb[4];
        #pragma unroll
        for (int mt = 0; mt < 4; ++mt) a[mt] = *(const f16x8*)&As[(wr * 64 + mt * 16 + cc) * 32 + g * 8];
        #pragma unroll
        for (int nt = 0; nt < 4; ++nt) bb[nt] = *(const f16x8*)&Bs[(wc * 64 + nt * 16 + cc) * 32 + g * 8];
        #pragma unroll
        for (int mt = 0; mt < 4; ++mt)
            #pragma unroll
            for (int nt = 0; nt < 4; ++nt)
                acc[mt][nt] = MFMA16(a[mt], bb[nt], acc[mt][nt]);
    }

    if (z < 2) {
        f16_t* out = (z == 0) ? Qo : Ko;
        // fold attention scale 1/sqrt(512) into Q
        const float osc = (z == 0) ? 0.044194173824159216f : 1.0f;
        #pragma unroll
        for (int nt = 0; nt < 4; ++nt) {
            float bval = bias[n0 + wc * 64 + nt * 16 + cc];
            #pragma unroll
            for (int mt = 0; mt < 4; ++mt)
                #pragma unroll
                for (int i = 0; i < 4; ++i) {
                    long m = m0 + wr * 64 + mt * 16 + 4 * g + i;
                    long n = n0 + wc * 64 + nt * 16 + cc;
                    out[m * 512 + n] = (f16_t)((acc[mt][nt][i] + bval) * osc);
                }
        }
    } else {
        #pragma unroll
        for (int mt = 0; mt < 4; ++mt)
            #pragma unroll
            for (int i = 0; i < 4; ++i) {
                long m = m0 + wr * 64 + mt * 16 + 4 * g + i;   // d index
                float bval = bias[m];
                #pragma unroll
                for (int nt = 0; nt < 4; ++nt) {
                    long sg = n0 + wc * 64 + nt * 16 + cc;
                    long bidx = sg >> 11, sl = sg & 2047;
                    Vto[bidx * (512L * 2048) + m * 2048 + sl] = (f16_t)(acc[mt][nt][i] + bval);
                }
            }
    }
}

// ---------------- 3) flash attention v4 ----------------
// LDS per buffer: K 32KB linear rows (content XOR-swizzled per row), V 40KB
// stride-5 slots.
//   K: slot(row,col) = row*64 + col; holds K[row][chunk col ^ (row&7)]
//      read: lane (cc,g), chunk u -> addr cc*1024 + ((u*4+g)^(cc&7))*16
//            = u*64 + glo*16 + (+/-)s74*64  -> two bases, imm offsets.
//   V: slot(d,c) = 5*d + c (c=0..3 data, c=4 hole); holds Vt chunk (d,c)
__global__ __launch_bounds__(512, 2) void attn_kernel(
    const f16_t* __restrict__ Q, const f16_t* __restrict__ K,
    const f16_t* __restrict__ Vt, float* __restrict__ out)
{
    extern __shared__ __align__(16) char smem[];
    char* KsB = smem;                          // [2][32768]
    char* VsB = smem + 65536;                  // [2][40960]
    f16_t* PlB = (f16_t*)(smem + 147456);      // [8][16][40] f16

    const int tid = threadIdx.x;
    const int w = tid >> 6, lane = tid & 63;
    const int g = lane >> 4, cc = lane & 15;
    // XCD-aware swizzle: 256 blocks, 8 XCDs -> each XCD owns 2 batches
    const int bx = (blockIdx.x & 7) * 32 + (blockIdx.x >> 3);
    const int b = bx >> 4, qt = bx & 15;
    const long qrow = (long)b * 2048 + qt * 128 + w * 16;

    const int s7 = cc & 7;             // K read-side swizzle bits (row = cc)
    const int s74 = (cc >> 2) & 1;     // bit 2 of s7
    const int glo = g ^ (cc & 3);      // low 2 bits of swizzled chunk

    // Q fragments: plain chunk order (v3's per-lane index permutation removed)
    f16x8 qf[16];
    {
        const f16_t* qp = Q + (qrow + cc) * 512;
        #pragma unroll
        for (int u = 0; u < 16; ++u) qf[u] = *(const f16x8*)(qp + u * 32 + g * 8);
    }

    f32x4 O[32];
    #pragma unroll
    for (int t = 0; t < 32; ++t) O[t] = (f32x4){0.f, 0.f, 0.f, 0.f};
    float m_[4], l_[4];
    #pragma unroll
    for (int i = 0; i < 4; ++i) { m_[i] = -__builtin_inff(); l_[i] = 0.f; }

    const f16_t* Kb = K + (long)b * 2048 * 512;
    const f16_t* Vb = Vt + (long)b * 512 * 2048;

    // ---- staging sources (coalesced) ----
    // K: wave-instr (w,it) loads full row r = w*4+it (1KB); lane's chunk = lane ^ (r&7)
    const f16_t* ksrc[4];
    #pragma unroll
    for (int it = 0; it < 4; ++it) {
        int r = w * 4 + it;
        ksrc[it] = Kb + (long)r * 512 + ((lane ^ (r & 7)) << 3);
    }
    // V: slot s = w*320 + it*64 + lane; d = s/5, c = s%5 (c==4 -> dup of c=3)
    const f16_t* vsrc[5];
    #pragma unroll
    for (int it = 0; it < 5; ++it) {
        int s = w * 320 + it * 64 + lane;
        int d = s / 5, c = s - d * 5;
        if (c > 3) c = 3;
        vsrc[it] = Vb + (long)d * 2048 + c * 8;
    }
    const int kdst = w * 4096;     // wave-uniform LDS dest base
    const int vdst = w * 5120;

    // prologue: stage tile 0 into buf 0
    #pragma unroll
    for (int it = 0; it < 4; ++it) {
        gload_lds16(ksrc[it], KsB + kdst + it * 1024);
        ksrc[it] += 32 * 512;
    }
    #pragma unroll
    for (int it = 0; it < 5; ++it) {
        gload_lds16(vsrc[it], VsB + vdst + it * 1024);
        vsrc[it] += 32;
    }
    asm volatile("s_waitcnt vmcnt(0)" ::: "memory");
    __syncthreads();

    const int krdE = cc * 1024 + (glo << 4) + (s74 << 6);   // even-u base
    const int krdO = cc * 1024 + (glo << 4) - (s74 << 6);   // odd-u base
    const int vrd  = (5 * cc + g) << 4;                      // PV read base

    int cur = 0;
    for (int t = 0; t < 64; ++t) {
        // issue next-tile loads (async, other buffer) BEFORE compute
        if (t < 63) {
            char* kd = KsB + (cur ^ 1) * 32768 + kdst;
            char* vd = VsB + (cur ^ 1) * 40960 + vdst;
            #pragma unroll
            for (int it = 0; it < 4; ++it) {
                gload_lds16(ksrc[it], kd + it * 1024);
                ksrc[it] += 32 * 512;
            }
            #pragma unroll
            for (int it = 0; it < 5; ++it) {
                gload_lds16(vsrc[it], vd + it * 1024);
                vsrc[it] += 32;
            }
        }

        const char* KcE = KsB + cur * 32768 + krdE;
        const char* KcO = KsB + cur * 32768 + krdO;
        const char* Vc  = VsB + cur * 40960 + vrd;

        // S[16 q][32 kv]: two 16x16 kv-tiles, K=512 over 16 chunks
        f32x4 s0 = (f32x4){0.f, 0.f, 0.f, 0.f}, s1 = (f32x4){0.f, 0.f, 0.f, 0.f};
        __builtin_amdgcn_s_setprio(1);
        #pragma unroll
        for (int u = 0; u < 16; u += 2) {
            f16x8 k0a = *(const f16x8*)(KcE + u * 64);
            f16x8 k1a = *(const f16x8*)(KcE + u * 64 + 16384);
            f16x8 k0b = *(const f16x8*)(KcO + (u + 1) * 64);
            f16x8 k1b = *(const f16x8*)(KcO + (u + 1) * 64 + 16384);
            s0 = MFMA16(qf[u], k0a, s0);
            s1 = MFMA16(qf[u], k1a, s1);
            s0 = MFMA16(qf[u + 1], k0b, s0);
            s1 = MFMA16(qf[u + 1], k1b, s1);
        }
        __builtin_amdgcn_s_setprio(0);

        // online softmax (Q pre-scaled); lane holds rows q=4g+i, col kv=cc (+16)
        float rmax[4];
        #pragma unroll
        for (int i = 0; i < 4; ++i) rmax[i] = fmaxf(s0[i], s1[i]);
        #pragma unroll
        for (int off = 1; off < 16; off <<= 1) {
            #pragma unroll
            for (int i = 0; i < 4; ++i)
                rmax[i] = fmaxf(rmax[i], __shfl_xor(rmax[i], off, 64));
        }
        // defer-max (T13): only raise the running max when it grew by > 6
        float al[4]; bool chg = false;
        #pragma unroll
        for (int i = 0; i < 4; ++i) {
            bool upd = rmax[i] > m_[i] + 6.0f;
            al[i] = upd ? __expf(m_[i] - rmax[i]) : 1.0f;
            if (upd) m_[i] = rmax[i];
            chg = chg || upd;
        }
        float rs[4];
        #pragma unroll
        for (int i = 0; i < 4; ++i) {
            float e0 = __expf(s0[i] - m_[i]);
            float e1 = __expf(s1[i] - m_[i]);
            rs[i] = e0 + e1;
            PlB[(w * 16 + 4 * g + i) * 40 + cc]      = (f16_t)e0;
            PlB[(w * 16 + 4 * g + i) * 40 + 16 + cc] = (f16_t)e1;
        }
        #pragma unroll
        for (int off = 1; off < 16; off <<= 1) {
            #pragma unroll
            for (int i = 0; i < 4; ++i)
                rs[i] += __shfl_xor(rs[i], off, 64);
        }
        if (__any(chg)) {
            #pragma unroll
            for (int i = 0; i < 4; ++i) l_[i] *= al[i];
            #pragma unroll
            for (int t2 = 0; t2 < 32; ++t2) {
                #pragma unroll
                for (int i = 0; i < 4; ++i) O[t2][i] *= al[i];
            }
        }
        #pragma unroll
        for (int i = 0; i < 4; ++i) l_[i] += rs[i];

        // PV: A = P (m=q, k=kv), B = V[d][kv] at stride-5 slots (imm offsets)
        f16x8 pf = *(const f16x8*)&PlB[(w * 16 + cc) * 40 + g * 8];
        __builtin_amdgcn_s_setprio(1);
        #pragma unroll
        for (int nt = 0; nt < 32; ++nt) {
            f16x8 vf = *(const f16x8*)(Vc + nt * 1280);
            O[nt] = MFMA16(pf, vf, O[nt]);
        }
        __builtin_amdgcn_s_setprio(0);

        asm volatile("s_waitcnt vmcnt(0)" ::: "memory");
        __syncthreads();
        cur ^= 1;
    }

    float* ob = out + (long)b * 2048 * 512 + (long)(qt * 128 + w * 16) * 512;
    #pragma unroll
    for (int nt = 0; nt < 32; ++nt) {
        #pragma unroll
        for (int i = 0; i < 4; ++i) {
            ob[(long)(4 * g + i) * 512 + nt * 16 + cc] = O[nt][i] * (1.0f / l_[i]);
        }
    }
}

// ---------------- launch ----------------
extern "C" void kernel_launch(void* const* d_in, const int* in_sizes, int n_in,
                              void* d_out, int out_size, void* d_ws, size_t ws_size,
                              hipStream_t stream)
{
    (void)in_sizes; (void)n_in; (void)out_size; (void)ws_size;
    const float* xq = (const float*)d_in[0];
    const float* xk = (const float*)d_in[1];
    const float* xv = (const float*)d_in[2];
    const float* Wq = (const float*)d_in[3];
    const float* bq = (const float*)d_in[4];
    const float* Wk = (const float*)d_in[5];
    const float* bk = (const float*)d_in[6];
    const float* Wv = (const float*)d_in[7];
    const float* bv = (const float*)d_in[8];
    float* out = (float*)d_out;

    f16_t* ws = (f16_t*)d_ws;
    f16_t* WTq = ws;
    f16_t* WTk = WTq + 512L * 512;
    f16_t* WTv = WTk + 512L * 512;
    f16_t* Qb  = WTv + 512L * 512;
    f16_t* Kb  = Qb + 32768L * 512;
    f16_t* Vtb = Kb + 32768L * 512;

    wt_kernel<<<3072, 256, 0, stream>>>(Wq, Wk, Wv, WTq, WTk, WTv);

    dim3 pgrid(1024, 1, 3);
    proj_kernel<<<pgrid, 256, 0, stream>>>(xq, xk, xv, WTq, WTk, WTv,
                                           bq, bk, bv, Qb, Kb, Vtb);

    // dynamic LDS: 2x32KB K + 2x40KB V + 10.25KB P = 157696 B
    attn_kernel<<<256, 512, 157696, stream>>>(Qb, Kb, Vtb, out);
}